// Round 5
// baseline (1111.938 us; speedup 1.0000x reference)
//
#include <hip/hip_runtime.h>
#include <stdint.h>

// M-RNN bidirectional GRU imputation for MI355X (gfx950).
// B=512, T=128, V=59, H=512. bf16 MFMA + fp32 state in registers.
// Persistent recurrence: register-direct A-fragments (no LDS A staging, one
// __syncthreads per step), monotone per-producer flags instead of barriers.
// h stores + flags are MALL-coherent (sc0 sc1); h/x loads are normal cached.

typedef unsigned short ushort_t;
typedef __bf16 bf16x8 __attribute__((ext_vector_type(8)));
typedef float f32x4 __attribute__((ext_vector_type(4)));
typedef unsigned int u32x4 __attribute__((ext_vector_type(4)));

__device__ __forceinline__ ushort_t f2bf(float f) {
    union { float f; uint32_t u; } c; c.f = f;
    uint32_t u = c.u;
    uint32_t r = (u + 0x7FFFu + ((u >> 16) & 1u)) >> 16;
    return (ushort_t)r;
}

__device__ __forceinline__ void store_b16_mall(void* p, unsigned v) {
    asm volatile("global_store_short %0, %1, off sc0 sc1"
                 :: "v"(p), "v"(v) : "memory");
}

// synchronous 16-flag read (one 64B line), MALL-coherent; drains vmcnt.
__device__ __forceinline__ void load_flags16(const unsigned* p,
                                             u32x4& a, u32x4& b, u32x4& c, u32x4& d) {
    asm volatile("global_load_dwordx4 %0, %4, off sc0 sc1\n\t"
                 "global_load_dwordx4 %1, %4, off offset:16 sc0 sc1\n\t"
                 "global_load_dwordx4 %2, %4, off offset:32 sc0 sc1\n\t"
                 "global_load_dwordx4 %3, %4, off offset:48 sc0 sc1\n\t"
                 "s_waitcnt vmcnt(0)"
                 : "=v"(a), "=v"(b), "=v"(c), "=v"(d) : "v"(p) : "memory");
}

__device__ __forceinline__ float fast_sigmoid(float x) {
    float e = __expf(-x);
    return __builtin_amdgcn_rcpf(1.f + e);
}
__device__ __forceinline__ float fast_tanh(float x) {
    float xc = fminf(fmaxf(x, -15.f), 15.f);
    float e = __expf(-2.f * xc);
    return (1.f - e) * __builtin_amdgcn_rcpf(1.f + e);
}

// ---------------------------------------------------------------------------
// prep_small: flags, slot-0 zeros, bf16 weights, post weights
// ---------------------------------------------------------------------------
__global__ void prep_small(const float* __restrict__ Wih, const float* __restrict__ Whh,
                           const float* __restrict__ Wh,
                           const float* __restrict__ Wf, const float* __restrict__ bf_,
                           const float* __restrict__ Wc, const float* __restrict__ bc,
                           const float* __restrict__ Wi, const float* __restrict__ bi,
                           ushort_t* __restrict__ WhhB, ushort_t* __restrict__ WihB,
                           ushort_t* __restrict__ WhpB,
                           ushort_t* __restrict__ hf0, ushort_t* __restrict__ hb0,
                           float* __restrict__ hstate,
                           ushort_t* __restrict__ Wpost1, ushort_t* __restrict__ Wpost2,
                           float* __restrict__ bcP, float* __restrict__ biP,
                           unsigned* __restrict__ flags)
{
    long long gid = (long long)blockIdx.x * blockDim.x + threadIdx.x;
    long long stride = (long long)gridDim.x * blockDim.x;

    for (long long i = gid; i < 16 * 32; i += stride) flags[i] = 0u;
    for (long long i = gid; i < 1024LL * 512; i += stride) hstate[i] = 0.f;
    for (long long i = gid; i < 512LL * 512; i += stride) { hf0[i] = 0; hb0[i] = 0; }
    for (long long i = gid; i < 1536LL * 512; i += stride) WhhB[i] = f2bf(Whh[i]);
    for (long long i = gid; i < 1536LL * 192; i += stride) {
        int n = (int)(i / 192), c = (int)(i % 192);
        WihB[i] = (c < 177) ? f2bf(Wih[n * 177 + c]) : (ushort_t)0;
    }
    for (long long i = gid; i < 64LL * 1024; i += stride) {
        int n = (int)(i >> 10), k = (int)(i & 1023);
        WhpB[i] = (n < 59) ? f2bf(Wh[n * 1024 + k]) : (ushort_t)0;
    }
    for (long long i = gid; i < 64LL * 192; i += stride) {
        int n = (int)(i / 192), c = (int)(i % 192);
        float w = 0.f;
        if (n < 59) {
            if (c < 59)       w = (c == n) ? 0.f : Wf[n * 59 + c];
            else if (c < 118) w = Wc[n * 118 + (c - 59)];
            else if (c < 177) w = Wc[n * 118 + 59 + (c - 118)];
        }
        Wpost1[i] = f2bf(w);
    }
    for (long long i = gid; i < 64LL * 64; i += stride) {
        int n = (int)(i >> 6), k = (int)(i & 63);
        Wpost2[i] = (n < 59 && k < 59) ? f2bf(Wi[n * 59 + k]) : (ushort_t)0;
    }
    for (long long i = gid; i < 64; i += stride) {
        bcP[i] = (i < 59) ? (bf_[i] + bc[i]) : 0.f;
        biP[i] = (i < 59) ? bi[i] : 0.f;
    }
}

// ---------------------------------------------------------------------------
// prep_panels: xcat_f / xcat_b / pcat (grid-stride over rows)
// ---------------------------------------------------------------------------
__global__ __launch_bounds__(192)
void prep_panels(const float* __restrict__ values, const float* __restrict__ masks,
                 const float* __restrict__ deltas_f, const float* __restrict__ deltas_b,
                 ushort_t* __restrict__ xcat_f, ushort_t* __restrict__ xcat_b,
                 ushort_t* __restrict__ pcat)
{
    const int c = threadIdx.x;             // 0..191
    for (int row = blockIdx.x; row < 65536; row += gridDim.x) {
        const int b = row >> 7, t = row & 127;
        const int tr = 127 - t;
        const long long rowr = (long long)b * 128 + tr;

        float vf = 0.f;
        if (c < 59)       vf = values  [(long long)row * 59 + c];
        else if (c < 118) vf = masks   [(long long)row * 59 + (c - 59)];
        else if (c < 177) vf = deltas_f[(long long)row * 59 + (c - 118)];
        xcat_f[((size_t)t * 512 + b) * 192 + c] = (c < 177) ? f2bf(vf) : (ushort_t)0;

        float vb = 0.f;
        if (c < 59)       vb = values  [rowr * 59 + c];
        else if (c < 118) vb = masks   [rowr * 59 + (c - 59)];
        else if (c < 177) vb = deltas_b[(long long)row * 59 + (c - 118)];
        xcat_b[((size_t)t * 512 + b) * 192 + c] = (c < 177) ? f2bf(vb) : (ushort_t)0;

        if (c < 59)
            pcat[(size_t)row * 192 + c] = f2bf(values[(long long)row * 59 + c]);
        else if (c >= 118 && c < 177)
            pcat[(size_t)row * 192 + c] = f2bf(masks[(long long)row * 59 + (c - 118)]);
        else if (c >= 177)
            pcat[(size_t)row * 192 + c] = 0;
    }
}

// ---------------------------------------------------------------------------
// Persistent recurrence: 127 GRU steps, both directions.
// 256 blocks x 512 thr, 1 block/CU. Weights LDS-resident (96x704 swizzled,
// 135168 B). A-fragments register-direct from global (L1/L2-cached).
// Sync: per-group 16 monotone flags (sc0 sc1); h stores sc0 sc1.
// ---------------------------------------------------------------------------
__device__ __forceinline__ void gates3(const ushort_t* __restrict__ Bq, int off,
                                       bf16x8 a, f32x4& accR, f32x4& accZ, f32x4& accT)
{
    bf16x8 b0 = *(const bf16x8*)(Bq + off);
    bf16x8 b1 = *(const bf16x8*)(Bq + 22528 + off);   // +32*704
    bf16x8 b2 = *(const bf16x8*)(Bq + 45056 + off);   // +64*704
    accR = __builtin_amdgcn_mfma_f32_16x16x32_bf16(a, b0, accR, 0, 0, 0);
    accZ = __builtin_amdgcn_mfma_f32_16x16x32_bf16(a, b1, accZ, 0, 0, 0);
    accT = __builtin_amdgcn_mfma_f32_16x16x32_bf16(a, b2, accT, 0, 0, 0);
}

__global__ __launch_bounds__(512)
void recurrence_kernel(const ushort_t* __restrict__ WhhB, const ushort_t* __restrict__ WihB,
                       const float* __restrict__ bih, const float* __restrict__ bhh,
                       const ushort_t* __restrict__ xcat_f, const ushort_t* __restrict__ xcat_b,
                       ushort_t* __restrict__ hfS, ushort_t* __restrict__ hbS,
                       unsigned* __restrict__ flags)
{
    extern __shared__ char smem_c[];
    ushort_t* Bw = (ushort_t*)smem_c;          // 96 x 704, col-chunk swizzled

    const int tid  = threadIdx.x;
    const int blk  = blockIdx.x;
    const int ublk = blk & 15;
    const int mblk = blk >> 4;
    const int u0   = ublk * 32;
    const bool fwd = (mblk < 8);
    const int rbase = (fwd ? mblk : mblk - 8) * 64;
    const ushort_t* xbase = fwd ? xcat_f : xcat_b;
    ushort_t* hS = fwd ? hfS : hbS;
    unsigned* gflag = flags + (unsigned)mblk * 32;   // 16 u32, 128B apart per group

    // weight preload (cached): row g*32+u -> [Whh(512) | Wih(192)], swizzled
    for (int i = tid; i < 96 * 88; i += 512) {
        int row = i / 88, q = i - row * 88;
        int g = row >> 5, u = u0 + (row & 31);
        const ushort_t* src = (q < 64)
            ? WhhB + ((size_t)(g * 512 + u)) * 512 + q * 8
            : WihB + ((size_t)(g * 512 + u)) * 192 + (q - 64) * 8;
        int qs = q ^ (row & 7);
        *(u32x4*)&Bw[row * 704 + qs * 8] = *(const u32x4*)src;
    }

    const int lane = tid & 63, wv = tid >> 6;
    const int mt = wv >> 1, tc = wv & 1;
    const int l15 = lane & 15, lhi = lane >> 4;
    const int aSw = l15 & 7;
    const int arowA = mt * 16 + l15;           // A-row within block tile

    // per-thread LDS B bases for ks=0 (j=lhi) and ks=32 (j=4+lhi)
    const ushort_t* Bq0 = Bw + (tc * 16 + l15) * 704 + ((lhi ^ aSw) * 8);
    const ushort_t* Bq1 = Bw + (tc * 16 + l15) * 704 + (((4 + lhi) ^ aSw) * 8);

    const int u = u0 + tc * 16 + l15;
    const float bR  = bih[u] + bhh[u];
    const float bZ  = bih[512 + u] + bhh[512 + u];
    const float bNX = bih[1024 + u];
    const float bNH = bhh[1024 + u];

    f32x4 hreg = {0.f, 0.f, 0.f, 0.f};
    f32x4 zero = {0.f, 0.f, 0.f, 0.f};

    __syncthreads();   // weights staged

    for (int t = 0; t < 127; ++t) {
        const ushort_t* hsrc = hS + (size_t)t * 262144;
        ushort_t* hdst = hS + (size_t)(t + 1) * 262144;
        const ushort_t* xsrc = xbase + (size_t)t * 98304;

        f32x4 accR = zero, accZ = zero, accNH = zero, accNX = zero;

        // ---- x positions (no dependency on other blocks) ----
        const ushort_t* xA = xsrc + (size_t)(rbase + arowA) * 192 + lhi * 8;
        #pragma unroll
        for (int cx = 0; cx < 3; ++cx) {
            bf16x8 a0 = *(const bf16x8*)(xA + cx * 64);
            bf16x8 a1 = *(const bf16x8*)(xA + cx * 64 + 32);
            gates3(Bq0, 512 + cx * 64, a0, accR, accZ, accNX);
            gates3(Bq1, 512 + cx * 64, a1, accR, accZ, accNX);
        }

        // ---- flag wait: all 16 producers of this group have written slot t ----
        {
            const unsigned ut = (unsigned)t;
            u32x4 fA, fB, fC, fD;
            for (;;) {
                load_flags16(gflag, fA, fB, fC, fD);
                unsigned ok = (fA[0] >= ut) & (fA[1] >= ut) & (fA[2] >= ut) & (fA[3] >= ut)
                            & (fB[0] >= ut) & (fB[1] >= ut) & (fB[2] >= ut) & (fB[3] >= ut)
                            & (fC[0] >= ut) & (fC[1] >= ut) & (fC[2] >= ut) & (fC[3] >= ut)
                            & (fD[0] >= ut) & (fD[1] >= ut) & (fD[2] >= ut) & (fD[3] >= ut);
                if (ok) break;
                __builtin_amdgcn_s_sleep(1);
            }
        }

        // ---- h positions (normal cached loads; L1 absorbs tc-pair reuse) ----
        const ushort_t* hA = hsrc + (size_t)(rbase + arowA) * 512 + lhi * 8;
        #pragma unroll
        for (int cc = 0; cc < 8; ++cc) {
            bf16x8 a0 = *(const bf16x8*)(hA + cc * 64);
            bf16x8 a1 = *(const bf16x8*)(hA + cc * 64 + 32);
            gates3(Bq0, cc * 64, a0, accR, accZ, accNH);
            gates3(Bq1, cc * 64, a1, accR, accZ, accNH);
        }

        // ---- GRU cell epilogue; fp32 state in registers; h out via MALL ----
        #pragma unroll
        for (int reg = 0; reg < 4; ++reg) {
            int m = rbase + mt * 16 + lhi * 4 + reg;
            float rr = fast_sigmoid(accR[reg] + bR);
            float zz = fast_sigmoid(accZ[reg] + bZ);
            float nn = fast_tanh(accNX[reg] + bNX + rr * (accNH[reg] + bNH));
            float hnew = (1.f - zz) * nn + zz * hreg[reg];
            hreg[reg] = hnew;
            store_b16_mall(hdst + (size_t)m * 512 + u, (unsigned)f2bf(hnew));
        }

        asm volatile("s_waitcnt vmcnt(0)" ::: "memory");  // h stores at MALL
        __syncthreads();                                  // all waves' stores done
        if (tid == 0) {
            unsigned fv = (unsigned)(t + 1);
            asm volatile("global_store_dword %0, %1, off sc0 sc1"
                         :: "v"(gflag + ublk), "v"(fv) : "memory");
        }
    }
}

// ---------------------------------------------------------------------------
// Fallback step kernel (used only if cooperative launch unavailable)
// ---------------------------------------------------------------------------
__global__ __launch_bounds__(512)
void step_kernel(const ushort_t* __restrict__ hsrcF, const ushort_t* __restrict__ hsrcB,
                 ushort_t* __restrict__ hdstF, ushort_t* __restrict__ hdstB,
                 const ushort_t* __restrict__ xF, const ushort_t* __restrict__ xB,
                 const ushort_t* __restrict__ WhhB, const ushort_t* __restrict__ WihB,
                 const float* __restrict__ bih, const float* __restrict__ bhh,
                 float* __restrict__ hstate)
{
    __shared__ __align__(16) ushort_t As[64 * 64];
    __shared__ __align__(16) ushort_t Bs[96 * 64];

    const int tid  = threadIdx.x;
    const int ublk = blockIdx.x;
    const int mblk = blockIdx.y;
    const int u0   = ublk * 32;
    const bool fwd = (mblk < 8);
    const ushort_t* hsrc = fwd ? hsrcF : hsrcB;
    const ushort_t* xsrc = fwd ? xF : xB;
    ushort_t* hdst = fwd ? hdstF : hdstB;
    const int rbase = (fwd ? mblk : mblk - 8) * 64;

    const int lane = tid & 63, wv = tid >> 6;
    const int mt = wv >> 1, tc = wv & 1;
    const int l15 = lane & 15, lhi = lane >> 4;

    f32x4 zero = {0.f, 0.f, 0.f, 0.f};
    f32x4 accR = zero, accZ = zero, accNH = zero, accNX = zero;
    const int arow = tid >> 3, ac8 = (tid & 7) * 8;

    for (int chunk = 0; chunk < 11; ++chunk) {
        const bool ph1 = (chunk < 8);
        {
            const ushort_t* src = ph1
                ? hsrc + ((size_t)(rbase + arow)) * 512 + chunk * 64 + ac8
                : xsrc + ((size_t)(rbase + arow)) * 192 + (chunk - 8) * 64 + ac8;
            *(uint4*)&As[arow * 64 + ac8] = *(const uint4*)src;
        }
        {
            int rowB = tid >> 3; int c8 = (tid & 7) * 8;
            int g = rowB >> 5; int u = u0 + (rowB & 31);
            const ushort_t* src = ph1
                ? WhhB + ((size_t)(g * 512 + u)) * 512 + chunk * 64 + c8
                : WihB + ((size_t)(g * 512 + u)) * 192 + (chunk - 8) * 64 + c8;
            *(uint4*)&Bs[rowB * 64 + c8] = *(const uint4*)src;
            if (tid < 256) {
                int u2 = tid + 512;
                rowB = u2 >> 3; c8 = (u2 & 7) * 8;
                g = rowB >> 5; u = u0 + (rowB & 31);
                src = ph1
                    ? WhhB + ((size_t)(g * 512 + u)) * 512 + chunk * 64 + c8
                    : WihB + ((size_t)(g * 512 + u)) * 192 + (chunk - 8) * 64 + c8;
                *(uint4*)&Bs[rowB * 64 + c8] = *(const uint4*)src;
            }
        }
        __syncthreads();
        #pragma unroll
        for (int ks = 0; ks < 64; ks += 32) {
            bf16x8 a  = *(const bf16x8*)&As[(mt * 16 + l15) * 64 + ks + lhi * 8];
            bf16x8 b0 = *(const bf16x8*)&Bs[( 0 + tc * 16 + l15) * 64 + ks + lhi * 8];
            bf16x8 b1 = *(const bf16x8*)&Bs[(32 + tc * 16 + l15) * 64 + ks + lhi * 8];
            bf16x8 b2 = *(const bf16x8*)&Bs[(64 + tc * 16 + l15) * 64 + ks + lhi * 8];
            accR = __builtin_amdgcn_mfma_f32_16x16x32_bf16(a, b0, accR, 0, 0, 0);
            accZ = __builtin_amdgcn_mfma_f32_16x16x32_bf16(a, b1, accZ, 0, 0, 0);
            if (ph1) accNH = __builtin_amdgcn_mfma_f32_16x16x32_bf16(a, b2, accNH, 0, 0, 0);
            else     accNX = __builtin_amdgcn_mfma_f32_16x16x32_bf16(a, b2, accNX, 0, 0, 0);
        }
        __syncthreads();
    }

    const int u = u0 + tc * 16 + l15;
    const float bR  = bih[u] + bhh[u];
    const float bZ  = bih[512 + u] + bhh[512 + u];
    const float bNX = bih[1024 + u];
    const float bNH = bhh[1024 + u];
    #pragma unroll
    for (int reg = 0; reg < 4; ++reg) {
        int m = mblk * 64 + mt * 16 + lhi * 4 + reg;
        float r = 1.f / (1.f + __expf(-(accR[reg] + bR)));
        float z = 1.f / (1.f + __expf(-(accZ[reg] + bZ)));
        float n = tanhf(accNX[reg] + bNX + r * (accNH[reg] + bNH));
        size_t idx = (size_t)m * 512 + u;
        float hold = hstate[idx];
        float hnew = (1.f - z) * n + z * hold;
        hstate[idx] = hnew;
        size_t bloc = (size_t)(fwd ? m : m - 512) * 512 + u;
        hdst[bloc] = f2bf(hnew);
    }
}

// ---------------------------------------------------------------------------
// x_v = [hf, hb_rev] @ Wh^T + bh, written as bf16 into pcat cols 59..117
// ---------------------------------------------------------------------------
__global__ __launch_bounds__(256)
void xv_kernel(const ushort_t* __restrict__ hf, const ushort_t* __restrict__ hb,
               const ushort_t* __restrict__ WhpB, const float* __restrict__ bh,
               ushort_t* __restrict__ pcat)
{
    __shared__ __align__(16) ushort_t As[128 * 64];
    __shared__ __align__(16) ushort_t Bs[64 * 64];
    const int b = blockIdx.x;
    const int tid = threadIdx.x;
    const int lane = tid & 63, wv = tid >> 6;
    const int l15 = lane & 15, lhi = lane >> 4;

    f32x4 zero = {0.f, 0.f, 0.f, 0.f};
    f32x4 acc[2][4];
    #pragma unroll
    for (int i = 0; i < 2; ++i)
        #pragma unroll
        for (int j = 0; j < 4; ++j) acc[i][j] = zero;

    for (int chunk = 0; chunk < 16; ++chunk) {
        const bool fw = (chunk < 8);
        #pragma unroll
        for (int s = 0; s < 4; ++s) {
            int unit = tid + s * 256;
            int row = unit >> 3;
            int c8 = (unit & 7) * 8;
            const ushort_t* src = fw
                ? hf + ((size_t)row * 512 + b) * 512 + chunk * 64 + c8
                : hb + ((size_t)(127 - row) * 512 + b) * 512 + (chunk - 8) * 64 + c8;
            *(uint4*)&As[row * 64 + c8] = *(const uint4*)src;
        }
        #pragma unroll
        for (int s = 0; s < 2; ++s) {
            int unit = tid + s * 256;
            int row = unit >> 3;
            int c8 = (unit & 7) * 8;
            *(uint4*)&Bs[row * 64 + c8] =
                *(const uint4*)(WhpB + (size_t)row * 1024 + chunk * 64 + c8);
        }
        __syncthreads();
        #pragma unroll
        for (int ks = 0; ks < 64; ks += 32) {
            bf16x8 bfr[4];
            #pragma unroll
            for (int nt = 0; nt < 4; ++nt)
                bfr[nt] = *(const bf16x8*)&Bs[(nt * 16 + l15) * 64 + ks + lhi * 8];
            #pragma unroll
            for (int mt2 = 0; mt2 < 2; ++mt2) {
                bf16x8 a = *(const bf16x8*)&As[(wv * 32 + mt2 * 16 + l15) * 64 + ks + lhi * 8];
                #pragma unroll
                for (int nt = 0; nt < 4; ++nt)
                    acc[mt2][nt] = __builtin_amdgcn_mfma_f32_16x16x32_bf16(a, bfr[nt], acc[mt2][nt], 0, 0, 0);
            }
        }
        __syncthreads();
    }
    #pragma unroll
    for (int mt2 = 0; mt2 < 2; ++mt2) {
        #pragma unroll
        for (int nt = 0; nt < 4; ++nt) {
            int col = nt * 16 + l15;
            if (col < 59) {
                float bhc = bh[col];
                #pragma unroll
                for (int reg = 0; reg < 4; ++reg) {
                    int t = wv * 32 + mt2 * 16 + lhi * 4 + reg;
                    pcat[((size_t)b * 128 + t) * 192 + 59 + col] = f2bf(acc[mt2][nt][reg] + bhc);
                }
            }
        }
    }
}

// ---------------------------------------------------------------------------
// Fused post: two chained MFMA GEMMs + x_imp + loss partials
// ---------------------------------------------------------------------------
__global__ __launch_bounds__(256)
void post_kernel(const ushort_t* __restrict__ pcat,
                 const ushort_t* __restrict__ Wpost1, const ushort_t* __restrict__ Wpost2,
                 const float* __restrict__ bcP, const float* __restrict__ biP,
                 const float* __restrict__ values, const float* __restrict__ masks,
                 float* __restrict__ out, float* __restrict__ pnum, float* __restrict__ pden)
{
    __shared__ __align__(16) ushort_t A1[64 * 200];
    __shared__ __align__(16) ushort_t B1[64 * 200];
    __shared__ __align__(16) ushort_t B2[64 * 72];

    const int tid = threadIdx.x;
    const int blk = blockIdx.x;
    const int lane = tid & 63, wv = tid >> 6;
    const int l15 = lane & 15, lhi = lane >> 4;

    #pragma unroll
    for (int s = 0; s < 6; ++s) {
        int unit = tid + s * 256;
        int row = unit / 24, c8 = (unit % 24) * 8;
        *(uint4*)&A1[row * 200 + c8] =
            *(const uint4*)(pcat + ((size_t)blk * 64 + row) * 192 + c8);
        *(uint4*)&B1[row * 200 + c8] =
            *(const uint4*)(Wpost1 + (size_t)row * 192 + c8);
    }
    #pragma unroll
    for (int s = 0; s < 2; ++s) {
        int unit = tid + s * 256;
        int row = unit >> 3, c8 = (unit & 7) * 8;
        *(uint4*)&B2[row * 72 + c8] = *(const uint4*)(Wpost2 + (size_t)row * 64 + c8);
    }
    __syncthreads();

    f32x4 zero = {0.f, 0.f, 0.f, 0.f};
    f32x4 acc1[4];
    #pragma unroll
    for (int nt = 0; nt < 4; ++nt) acc1[nt] = zero;

    #pragma unroll
    for (int ks = 0; ks < 192; ks += 32) {
        bf16x8 a = *(const bf16x8*)&A1[(wv * 16 + l15) * 200 + ks + lhi * 8];
        #pragma unroll
        for (int nt = 0; nt < 4; ++nt) {
            bf16x8 bb = *(const bf16x8*)&B1[(nt * 16 + l15) * 200 + ks + lhi * 8];
            acc1[nt] = __builtin_amdgcn_mfma_f32_16x16x32_bf16(a, bb, acc1[nt], 0, 0, 0);
        }
    }
    __syncthreads();

    #pragma unroll
    for (int nt = 0; nt < 4; ++nt) {
        int col = nt * 16 + l15;
        float bcv = bcP[col];
        #pragma unroll
        for (int reg = 0; reg < 4; ++reg) {
            int row = wv * 16 + lhi * 4 + reg;
            A1[row * 72 + col] = f2bf(acc1[nt][reg] + bcv);
        }
    }
    __syncthreads();

    f32x4 acc2[4];
    #pragma unroll
    for (int nt = 0; nt < 4; ++nt) acc2[nt] = zero;
    #pragma unroll
    for (int ks = 0; ks < 64; ks += 32) {
        bf16x8 a = *(const bf16x8*)&A1[(wv * 16 + l15) * 72 + ks + lhi * 8];
        #pragma unroll
        for (int nt = 0; nt < 4; ++nt) {
            bf16x8 bb = *(const bf16x8*)&B2[(nt * 16 + l15) * 72 + ks + lhi * 8];
            acc2[nt] = __builtin_amdgcn_mfma_f32_16x16x32_bf16(a, bb, acc2[nt], 0, 0, 0);
        }
    }

    float biR[4];
    #pragma unroll
    for (int nt = 0; nt < 4; ++nt) biR[nt] = biP[nt * 16 + l15];

    #pragma unroll
    for (int reg = 0; reg < 4; ++reg) {
        size_t rowg = (size_t)blk * 64 + wv * 16 + lhi * 4 + reg;
        float esum = 0.f, dsum = 0.f;
        #pragma unroll
        for (int nt = 0; nt < 4; ++nt) {
            int col = nt * 16 + l15;
            if (col < 59) {
                float imp = acc2[nt][reg] + biR[nt];
                float v = values[rowg * 59 + col];
                float m = masks [rowg * 59 + col];
                out[rowg * 59 + col] = m * v + (1.f - m) * imp;
                esum += fabsf(v - imp) * m;
                dsum += m;
            }
        }
        #pragma unroll
        for (int o = 1; o < 16; o <<= 1) {
            esum += __shfl_xor(esum, o);
            dsum += __shfl_xor(dsum, o);
        }
        if (l15 == 0) { pnum[rowg] = esum; pden[rowg] = dsum; }
    }
}

// ---------------------------------------------------------------------------
// loss reduction: sum_t ( sum_b num / (sum_b den + 1e-5) )
// ---------------------------------------------------------------------------
__global__ __launch_bounds__(512)
void loss_kernel(const float* __restrict__ pnum, const float* __restrict__ pden,
                 float* __restrict__ out)
{
    __shared__ float sn[512], sd[512];
    int tid = threadIdx.x;
    int t = tid & 127, q = tid >> 7;
    float a = 0.f, b = 0.f;
    for (int i = 0; i < 128; ++i) {
        int bb = q * 128 + i;
        a += pnum[(size_t)bb * 128 + t];
        b += pden[(size_t)bb * 128 + t];
    }
    sn[tid] = a; sd[tid] = b;
    __syncthreads();
    if (q == 0) {
        float A = sn[t] + sn[128 + t] + sn[256 + t] + sn[384 + t];
        float B = sd[t] + sd[128 + t] + sd[256 + t] + sd[384 + t];
        sn[t] = A / (B + 1e-5f);
    }
    __syncthreads();
    if (tid == 0) {
        float s = 0.f;
        for (int i = 0; i < 128; ++i) s += sn[i];
        out[3866624] = s;   // B*T*V
    }
}

// ---------------------------------------------------------------------------
extern "C" void kernel_launch(void* const* d_in, const int* in_sizes, int n_in,
                              void* d_out, int out_size, void* d_ws, size_t ws_size,
                              hipStream_t stream)
{
    const float* values   = (const float*)d_in[0];
    const float* masks    = (const float*)d_in[1];
    const float* deltas_f = (const float*)d_in[2];
    const float* deltas_b = (const float*)d_in[3];
    const float* Wih = (const float*)d_in[4];
    const float* Whh = (const float*)d_in[5];
    const float* bih = (const float*)d_in[6];
    const float* bhh = (const float*)d_in[7];
    const float* Wh  = (const float*)d_in[8];
    const float* bh  = (const float*)d_in[9];
    const float* Wf  = (const float*)d_in[10];
    const float* bf_ = (const float*)d_in[11];
    const float* Wc  = (const float*)d_in[12];
    const float* bc  = (const float*)d_in[13];
    const float* Wi  = (const float*)d_in[14];
    const float* bi  = (const float*)d_in[15];
    float* out = (float*)d_out;

    uint8_t* ws = (uint8_t*)d_ws;
    size_t off = 0;
    auto alloc = [&](size_t bytes) -> void* {
        void* p = ws + off;
        off = (off + bytes + 255) & ~((size_t)255);
        return p;
    };
    ushort_t* xcat_f = (ushort_t*)alloc(128ULL * 512 * 192 * 2);
    ushort_t* xcat_b = (ushort_t*)alloc(128ULL * 512 * 192 * 2);
    ushort_t* WhhB   = (ushort_t*)alloc(1536ULL * 512 * 2);
    ushort_t* WihB   = (ushort_t*)alloc(1536ULL * 192 * 2);
    ushort_t* WhpB   = (ushort_t*)alloc(64ULL * 1024 * 2);
    ushort_t* hfS    = (ushort_t*)alloc(128ULL * 512 * 512 * 2);
    ushort_t* hbS    = (ushort_t*)alloc(128ULL * 512 * 512 * 2);
    float*    hstate = (float*)alloc(1024ULL * 512 * 4);
    ushort_t* pcat   = (ushort_t*)alloc(65536ULL * 192 * 2);
    ushort_t* Wpost1 = (ushort_t*)alloc(64ULL * 192 * 2);
    ushort_t* Wpost2 = (ushort_t*)alloc(64ULL * 64 * 2);
    float*    bcP    = (float*)alloc(64 * 4);
    float*    biP    = (float*)alloc(64 * 4);
    float*    pnum   = (float*)alloc(65536ULL * 4);
    float*    pden   = (float*)alloc(65536ULL * 4);
    unsigned* flags  = (unsigned*)alloc(16 * 32 * 4);

    prep_small<<<1024, 256, 0, stream>>>(Wih, Whh, Wh, Wf, bf_, Wc, bc, Wi, bi,
                                         WhhB, WihB, WhpB, hfS, hbS, hstate,
                                         Wpost1, Wpost2, bcP, biP, flags);
    prep_panels<<<8192, 192, 0, stream>>>(values, masks, deltas_f, deltas_b,
                                          xcat_f, xcat_b, pcat);

    // Persistent recurrence (flag sync); fallback: 127 step launches
    const unsigned smemBytes = 96u * 704u * 2u;  // 135168 B
    hipError_t aerr = hipFuncSetAttribute((const void*)recurrence_kernel,
                                          hipFuncAttributeMaxDynamicSharedMemorySize,
                                          (int)smemBytes);
    hipError_t lerr = hipErrorUnknown;
    if (aerr == hipSuccess) {
        const ushort_t* a0 = WhhB; const ushort_t* a1 = WihB;
        const float* a2 = bih; const float* a3 = bhh;
        const ushort_t* a4 = xcat_f; const ushort_t* a5 = xcat_b;
        ushort_t* a6 = hfS; ushort_t* a7 = hbS;
        unsigned* a8 = flags;
        void* args[] = { &a0, &a1, &a2, &a3, &a4, &a5, &a6, &a7, &a8 };
        lerr = hipLaunchCooperativeKernel((const void*)recurrence_kernel,
                                          dim3(256), dim3(512), args, smemBytes, stream);
    }
    if (lerr != hipSuccess) {
        for (int t = 0; t < 127; ++t) {
            step_kernel<<<dim3(16, 16), 512, 0, stream>>>(
                hfS + (size_t)t * 512 * 512, hbS + (size_t)t * 512 * 512,
                hfS + (size_t)(t + 1) * 512 * 512, hbS + (size_t)(t + 1) * 512 * 512,
                xcat_f + (size_t)t * 512 * 192, xcat_b + (size_t)t * 512 * 192,
                WhhB, WihB, bih, bhh, hstate);
        }
    }

    xv_kernel<<<512, 256, 0, stream>>>(hfS, hbS, WhpB, bh, pcat);
    post_kernel<<<1024, 256, 0, stream>>>(pcat, Wpost1, Wpost2, bcP, biP,
                                          values, masks, out, pnum, pden);
    loss_kernel<<<1, 512, 0, stream>>>(pnum, pden, out);
}